// Round 5
// baseline (70.587 us; speedup 1.0000x reference)
//
#include <hip/hip_runtime.h>
#include <hip/hip_bf16.h>
#include <stdint.h>

typedef __attribute__((ext_vector_type(8))) short short8;
typedef __attribute__((ext_vector_type(8))) __bf16 bf16x8;
typedef __attribute__((ext_vector_type(4))) float f32x4;
typedef __attribute__((ext_vector_type(4))) float float4v;
typedef __attribute__((ext_vector_type(4))) unsigned short us4;
typedef unsigned int u32;
typedef __attribute__((address_space(3))) u32 lds_u32;
typedef const __attribute__((address_space(1))) u32 g_u32;

#define NSEQ 2048
#define L2E 1.44269504088896f

static __device__ __forceinline__ unsigned short f2bf(float x){
  union { float f; u32 u; } v; v.f = x;
  u32 r = v.u + 0x7fffu + ((v.u >> 16) & 1u);
  return (unsigned short)(r >> 16);
}
static __device__ __forceinline__ float bf2f(unsigned short s){
  union { float f; u32 u; } v; v.u = ((u32)s) << 16; return v.f;
}
static __device__ __forceinline__ void gload16(const void* g, void* l){
  __builtin_amdgcn_global_load_lds((g_u32*)g, (lds_u32*)l, 16, 0, 0);
}
static __device__ __forceinline__ f32x4 mfma16(bf16x8 a, bf16x8 b, f32x4 c){
  return __builtin_amdgcn_mfma_f32_16x16x32_bf16(a, b, c, 0, 0, 0);
}
static __device__ __forceinline__ bf16x8 ldfrag(const void* p){
  return *(const bf16x8*)p;
}
#define MEMFENCE() asm volatile("" ::: "memory")

// ---------------- kernel 1: convert inputs to bf16, transpose weights ----------------
__global__ __launch_bounds__(256) void cvt_kernel(const float* __restrict__ qx,
                           const float* __restrict__ kvx,
                           const float* __restrict__ Wq, const float* __restrict__ Wk,
                           const float* __restrict__ Wv, const float* __restrict__ Wg,
                           const float* __restrict__ Wo,
                           unsigned short* __restrict__ Xbq, unsigned short* __restrict__ Xbkv,
                           unsigned short* __restrict__ Wt4, unsigned short* __restrict__ Wot){
  __shared__ float T[64][65];
  int bid = blockIdx.x;
  if (bid < 512){
    int i4 = (bid*256 + threadIdx.x) * 4;
    float4v q = *(const float4v*)(qx + i4);
    float4v k = *(const float4v*)(kvx + i4);
    us4 qo, ko;
    #pragma unroll
    for (int j = 0; j < 4; ++j){ qo[j] = f2bf(q[j]); ko[j] = f2bf(k[j]); }
    *(us4*)(Xbq + i4) = qo;
    *(us4*)(Xbkv + i4) = ko;
  } else {
    int b2 = bid - 512;                     // 0..79
    int w = b2 >> 4, tile = b2 & 15, tr = tile >> 2, tc = tile & 3;
    const float* W = (w==0)?Wq:((w==1)?Wk:((w==2)?Wv:((w==3)?Wg:Wo)));
    int t = threadIdx.x;
    int rl = t >> 4, cq = t & 15;
    #pragma unroll
    for (int p = 0; p < 4; ++p){
      int r = p*16 + rl;
      float4v v = *(const float4v*)(W + (size_t)(tr*64 + r)*256 + tc*64 + cq*4);
      #pragma unroll
      for (int j = 0; j < 4; ++j) T[r][cq*4+j] = v[j];
    }
    __syncthreads();
    float s = (w==0) ? 0.17677669529663687f : 1.f;   // fold 1/sqrt(32) into Wq
    #pragma unroll
    for (int p = 0; p < 4; ++p){
      int o = p*16 + rl;
      us4 pk;
      #pragma unroll
      for (int j = 0; j < 4; ++j) pk[j] = f2bf(T[cq*4+j][o] * s);
      int og = tc*64 + o, ig = tr*64 + cq*4;
      if (w < 4) *(us4*)(Wt4 + (size_t)w*65536 + og*256 + ig) = pk;
      else       *(us4*)(Wot + (size_t)og*256 + ig) = pk;
    }
  }
}

// ---------------- kernel 2: fused QKVG projection GEMM ----------------
__global__ __launch_bounds__(256) void proj_kernel(const unsigned short* __restrict__ Xbq,
     const unsigned short* __restrict__ Xbkv, const unsigned short* __restrict__ Wt4,
     unsigned short* __restrict__ Qb, unsigned short* __restrict__ Kb,
     unsigned short* __restrict__ Vt, unsigned short* __restrict__ Gg){
  __shared__ unsigned short Asm[64*256];
  __shared__ unsigned short Bsm[64*256];
  int mt = blockIdx.x;            // 0..31
  int nt = blockIdx.y;            // 0..15
  int col0 = nt * 64;
  int w = col0 >> 8;              // 0=Q 1=K 2=V 3=G
  const unsigned short* A = (w==0 || w==3) ? Xbq : Xbkv;
  int tid = threadIdx.x, lane = tid & 63, wid = tid >> 6;
  const char* Ab = (const char*)A   + (size_t)mt*64*512;
  const char* Bb = (const char*)Wt4 + (size_t)col0*512;
  char* Asl = (char*)Asm; char* Bsl = (char*)Bsm;
  #pragma unroll
  for (int it = 0; it < 8; ++it){
    int o = it*4096 + wid*1024 + lane*16;
    int row = o >> 9, b = o & 511;
    int sb = (o & ~511) + (b ^ ((row & 15) << 4));
    gload16(Ab + sb, Asl + it*4096 + wid*1024);
    gload16(Bb + sb, Bsl + it*4096 + wid*1024);
  }
  __syncthreads();
  int ml = lane & 15, kg = lane >> 4;
  int m = wid*16 + ml;
  bf16x8 afr[8];
  #pragma unroll
  for (int ks = 0; ks < 8; ++ks)
    afr[ks] = ldfrag(Asl + m*512 + ((ks*64 + kg*16) ^ (ml << 4)));
  f32x4 acc[4];
  #pragma unroll
  for (int ct = 0; ct < 4; ++ct){
    acc[ct] = (f32x4){0.f,0.f,0.f,0.f};
    int oo = ct*16 + ml;
    #pragma unroll
    for (int ks = 0; ks < 8; ++ks){
      bf16x8 bfr = ldfrag(Bsl + oo*512 + ((ks*64 + kg*16) ^ (ml << 4)));
      acc[ct] = mfma16(afr[ks], bfr, acc[ct]);
    }
  }
  #pragma unroll
  for (int ct = 0; ct < 4; ++ct){
    int colg = col0 + ct*16 + ml;
    int cw = colg & 255, hh = cw >> 5, c = cw & 31;
    int n0 = mt*64 + wid*16 + kg*4;
    if (w == 2){
      us4 pk;
      pk[0]=f2bf(acc[ct][0]); pk[1]=f2bf(acc[ct][1]);
      pk[2]=f2bf(acc[ct][2]); pk[3]=f2bf(acc[ct][3]);
      *(us4*)((char*)Vt + ((size_t)(hh*32 + c)*NSEQ + n0)*2) = pk;
    } else {
      #pragma unroll
      for (int r = 0; r < 4; ++r){
        int n = n0 + r;
        float v = acc[ct][r];
        if (w == 0)      Qb[((size_t)hh*NSEQ + n)*32 + c] = f2bf(v);
        else if (w == 1) Kb[((size_t)hh*NSEQ + n)*32 + c] = f2bf(v);
        else             Gg[(size_t)n*256 + cw] = f2bf(1.f/(1.f + __expf(-v)));
      }
    }
  }
}

// ---------------- kernel 3: fused bias-attention, kv-split ----------------
// grid 1024 = 8 heads x 32 q-tiles(64) x 4 kv-chunks(512). 4 waves/block,
// 4 blocks/CU (LDS 40KB). Full-unroll 8-tile loop.
// FIFO-ordered issue (the round-4 bug): bias(t+1) is issued BEFORE KV(t+2)
// and consumed one tile later, so the pre-QK wait is exactly vmcnt(2)
// (KV(t+1) stays in flight) — no full drain anywhere except the last tile.
__global__ __launch_bounds__(256, 4) void attn_kernel(const unsigned short* __restrict__ Qb,
    const unsigned short* __restrict__ Kb, const unsigned short* __restrict__ Vt,
    const float* __restrict__ bias,
    float* __restrict__ Opart, float* __restrict__ Mpart, float* __restrict__ Lpart){
  __shared__ unsigned short Ksm[4][2048];   // [64 kv][32 c] bf16, 4 bufs
  __shared__ unsigned short Vsm[4][2048];   // [32 c][64 kv] bf16, 4 bufs
  __shared__ unsigned short Psm[4096];      // [64 q][64 kv] bf16 (wave-local rows)
  int bid = blockIdx.x;
  int h = bid >> 7, qt = (bid >> 2) & 31, ch = bid & 3;
  int q0 = qt * 64;
  int tid = threadIdx.x, lane = tid & 63, wid = tid >> 6;
  int ml = lane & 15, kg = lane >> 4;
  int qw = q0 + wid*16;
  bf16x8 qfr = ldfrag((const char*)Qb + (((size_t)h*NSEQ + qw + ml)*32 + kg*8)*2);
  const char* Kbase = (const char*)Kb + (size_t)h*NSEQ*32*2;
  const char* Vbase = (const char*)Vt + (size_t)h*32*NSEQ*2;
  // 4 per-row bias base pointers (row qw+kg*4+r, col chunk-start + ml);
  // after full unroll all further offsets are <4KB immediates.
  const float* bias_l = bias + (size_t)h*NSEQ*NSEQ + (size_t)(qw + kg*4)*NSEQ + ch*512 + ml;
  const float* br0 = bias_l;
  const float* br1 = bias_l + NSEQ;
  const float* br2 = bias_l + 2*NSEQ;
  const float* br3 = bias_l + 3*NSEQ;
  float mreg[4] = {-3e38f,-3e38f,-3e38f,-3e38f};
  float lreg[4] = {0.f,0.f,0.f,0.f};
  f32x4 oacc[2];
  oacc[0] = (f32x4){0.f,0.f,0.f,0.f};
  oacc[1] = (f32x4){0.f,0.f,0.f,0.f};

  auto stage = [&](int t, int buf){   // t = tile within chunk (0..7)
    int tg = ch*8 + t;                // global 64-kv tile
    int o = tid*16;
    int n = o >> 6, kb = o & 63;
    gload16(Kbase + (size_t)tg*4096 + (o & ~63) + (kb ^ (((n>>1)&3) << 4)),
            (char*)&Ksm[buf][0] + o);
    int c = o >> 7, vb = o & 127;
    gload16(Vbase + (size_t)c*4096 + (size_t)tg*128 + (vb ^ ((c&7) << 4)),
            (char*)&Vsm[buf][0] + o);
  };

  float bb[2][4][4];
  // prologue, FIFO order: bias(0) first (oldest), then KV(0), KV(1)
  #pragma unroll
  for (int ct = 0; ct < 4; ++ct){
    bb[0][ct][0] = br0[ct*16];
    bb[0][ct][1] = br1[ct*16];
    bb[0][ct][2] = br2[ct*16];
    bb[0][ct][3] = br3[ct*16];
  }
  MEMFENCE();
  stage(0, 0);
  stage(1, 1);
  #pragma unroll
  for (int t = 0; t < 8; ++t){
    int cur = t & 3;
    // forces bias(t)+KV(t) landed; leaves exactly KV(t+1) (2 loads) in flight.
    if (t == 7) asm volatile("s_waitcnt vmcnt(0)" ::: "memory");
    else        asm volatile("s_waitcnt vmcnt(2)" ::: "memory");
    __builtin_amdgcn_s_barrier();
    MEMFENCE();
    // issue bias(t+1) EARLY (before QK): a full tile of compute hides it
    if (t < 7){
      #pragma unroll
      for (int ct = 0; ct < 4; ++ct){
        bb[(t+1)&1][ct][0] = br0[(t+1)*64 + ct*16];
        bb[(t+1)&1][ct][1] = br1[(t+1)*64 + ct*16];
        bb[(t+1)&1][ct][2] = br2[(t+1)*64 + ct*16];
        bb[(t+1)&1][ct][3] = br3[(t+1)*64 + ct*16];
      }
    }
    MEMFENCE();
    // S = bias(t) [pre-landed regs] + Q K^T
    f32x4 s[4];
    #pragma unroll
    for (int ct = 0; ct < 4; ++ct){
      f32x4 b;
      #pragma unroll
      for (int r = 0; r < 4; ++r) b[r] = bb[t&1][ct][r];
      int n = ct*16 + ml;
      bf16x8 kfr = ldfrag((char*)&Ksm[cur][0] + n*64 + ((kg*16) ^ (((n>>1)&3) << 4)));
      s[ct] = mfma16(qfr, kfr, b);
    }
    MEMFENCE();
    if (t < 6) stage(t+2, (t+2) & 3);   // WAR-safe: 2 barriers since last read
    MEMFENCE();
    // online softmax (16 rows/wave; row r lives across 16 ml lanes)
    float mx[4];
    #pragma unroll
    for (int r = 0; r < 4; ++r){
      mx[r] = fmaxf(fmaxf(s[0][r], s[1][r]), fmaxf(s[2][r], s[3][r]));
    }
    #pragma unroll
    for (int d = 1; d < 16; d <<= 1){
      #pragma unroll
      for (int r = 0; r < 4; ++r) mx[r] = fmaxf(mx[r], __shfl_xor(mx[r], d));
    }
    float sc[4], rs[4];
    #pragma unroll
    for (int r = 0; r < 4; ++r){
      float mn = fmaxf(mreg[r], mx[r]);
      sc[r] = exp2f((mreg[r] - mn) * L2E);
      mreg[r] = mn;
      rs[r] = 0.f;
    }
    #pragma unroll
    for (int ct = 0; ct < 4; ++ct){
      #pragma unroll
      for (int r = 0; r < 4; ++r){
        float pv = exp2f((s[ct][r] - mreg[r]) * L2E);
        s[ct][r] = pv;
        rs[r] += pv;
      }
    }
    #pragma unroll
    for (int d = 1; d < 16; d <<= 1){
      #pragma unroll
      for (int r = 0; r < 4; ++r) rs[r] += __shfl_xor(rs[r], d);
    }
    #pragma unroll
    for (int r = 0; r < 4; ++r) lreg[r] = lreg[r]*sc[r] + rs[r];
    #pragma unroll
    for (int c2 = 0; c2 < 2; ++c2){
      #pragma unroll
      for (int r = 0; r < 4; ++r) oacc[c2][r] *= sc[r];
    }
    // P -> LDS (wave-local rows; same-wave write->read, lgkmcnt-ordered)
    #pragma unroll
    for (int ct = 0; ct < 4; ++ct){
      #pragma unroll
      for (int r = 0; r < 4; ++r){
        int q = wid*16 + kg*4 + r;
        int k = ct*16 + ml;
        *(unsigned short*)((char*)Psm + q*128 + ((k*2) ^ ((q&7) << 4))) = f2bf(s[ct][r]);
      }
    }
    // O += P V
    int qq = wid*16 + ml;
    #pragma unroll
    for (int ks = 0; ks < 2; ++ks){
      bf16x8 pfr = ldfrag((char*)Psm + qq*128 + ((ks*64 + kg*16) ^ ((qq&7) << 4)));
      #pragma unroll
      for (int c2 = 0; c2 < 2; ++c2){
        int c = c2*16 + ml;
        bf16x8 vfr = ldfrag((char*)&Vsm[cur][0] + c*128 + ((ks*64 + kg*16) ^ ((c&7) << 4)));
        oacc[c2] = mfma16(pfr, vfr, oacc[c2]);
      }
    }
    MEMFENCE();
  }
  // epilogue: partial results (unnormalized O, running m, running l)
  size_t pbase = ((size_t)(ch*8 + h)*NSEQ);
  #pragma unroll
  for (int c2 = 0; c2 < 2; ++c2){
    #pragma unroll
    for (int r = 0; r < 4; ++r){
      int q = qw + kg*4 + r;
      Opart[(pbase + q)*32 + c2*16 + ml] = oacc[c2][r];
    }
  }
  if (ml == 0){
    #pragma unroll
    for (int r = 0; r < 4; ++r){
      int q = qw + kg*4 + r;
      Mpart[pbase + q] = mreg[r];
      Lpart[pbase + q] = lreg[r];
    }
  }
}

// ---------------- kernel 3b: combine kv-chunks + gate ----------------
__global__ __launch_bounds__(256) void combine_kernel(const float* __restrict__ Opart,
    const float* __restrict__ Mpart, const float* __restrict__ Lpart,
    const unsigned short* __restrict__ Gg, unsigned short* __restrict__ Og){
  int n = blockIdx.x*8 + (threadIdx.x >> 5);
  int c = threadIdx.x & 31;
  #pragma unroll
  for (int h = 0; h < 8; ++h){
    float m0 = Mpart[(size_t)(0*8+h)*NSEQ + n], m1 = Mpart[(size_t)(1*8+h)*NSEQ + n];
    float m2 = Mpart[(size_t)(2*8+h)*NSEQ + n], m3 = Mpart[(size_t)(3*8+h)*NSEQ + n];
    float M = fmaxf(fmaxf(m0, m1), fmaxf(m2, m3));
    float e0 = exp2f((m0-M)*L2E), e1 = exp2f((m1-M)*L2E);
    float e2 = exp2f((m2-M)*L2E), e3 = exp2f((m3-M)*L2E);
    float L = Lpart[(size_t)(0*8+h)*NSEQ + n]*e0 + Lpart[(size_t)(1*8+h)*NSEQ + n]*e1
            + Lpart[(size_t)(2*8+h)*NSEQ + n]*e2 + Lpart[(size_t)(3*8+h)*NSEQ + n]*e3;
    float o = Opart[((size_t)(0*8+h)*NSEQ + n)*32 + c]*e0
            + Opart[((size_t)(1*8+h)*NSEQ + n)*32 + c]*e1
            + Opart[((size_t)(2*8+h)*NSEQ + n)*32 + c]*e2
            + Opart[((size_t)(3*8+h)*NSEQ + n)*32 + c]*e3;
    float g = bf2f(Gg[(size_t)n*256 + h*32 + c]);
    Og[(size_t)n*256 + h*32 + c] = f2bf(o / L * g);
  }
}

// ---------------- kernel 4: output projection ----------------
__global__ __launch_bounds__(256) void oproj_kernel(const unsigned short* __restrict__ Og,
    const unsigned short* __restrict__ Wot, float* __restrict__ out){
  __shared__ unsigned short Asm[64*256];
  __shared__ unsigned short Bsm[64*256];
  int mt = blockIdx.x, nt = blockIdx.y;
  int col0 = nt * 64;
  int tid = threadIdx.x, lane = tid & 63, wid = tid >> 6;
  const char* Ab = (const char*)Og  + (size_t)mt*64*512;
  const char* Bb = (const char*)Wot + (size_t)col0*512;
  char* Asl = (char*)Asm; char* Bsl = (char*)Bsm;
  #pragma unroll
  for (int it = 0; it < 8; ++it){
    int o = it*4096 + wid*1024 + lane*16;
    int row = o >> 9, b = o & 511;
    int sb = (o & ~511) + (b ^ ((row & 15) << 4));
    gload16(Ab + sb, Asl + it*4096 + wid*1024);
    gload16(Bb + sb, Bsl + it*4096 + wid*1024);
  }
  __syncthreads();
  int ml = lane & 15, kg = lane >> 4;
  int m = wid*16 + ml;
  bf16x8 afr[8];
  #pragma unroll
  for (int ks = 0; ks < 8; ++ks)
    afr[ks] = ldfrag(Asl + m*512 + ((ks*64 + kg*16) ^ (ml << 4)));
  f32x4 acc[4];
  #pragma unroll
  for (int ct = 0; ct < 4; ++ct){
    acc[ct] = (f32x4){0.f,0.f,0.f,0.f};
    int oo = ct*16 + ml;
    #pragma unroll
    for (int ks = 0; ks < 8; ++ks){
      bf16x8 bfr = ldfrag(Bsl + oo*512 + ((ks*64 + kg*16) ^ (ml << 4)));
      acc[ct] = mfma16(afr[ks], bfr, acc[ct]);
    }
  }
  #pragma unroll
  for (int ct = 0; ct < 4; ++ct){
    #pragma unroll
    for (int r = 0; r < 4; ++r){
      int mm = mt*64 + wid*16 + kg*4 + r;
      out[(size_t)mm*256 + col0 + ct*16 + ml] = acc[ct][r];
    }
  }
}

extern "C" void kernel_launch(void* const* d_in, const int* in_sizes, int n_in,
                              void* d_out, int out_size, void* d_ws, size_t ws_size,
                              hipStream_t stream) {
  const float* qx   = (const float*)d_in[0];
  const float* kvx  = (const float*)d_in[1];
  const float* bias = (const float*)d_in[2];
  const float* Wq   = (const float*)d_in[3];
  const float* Wk   = (const float*)d_in[4];
  const float* Wv   = (const float*)d_in[5];
  const float* Wg   = (const float*)d_in[6];
  const float* Wo   = (const float*)d_in[7];
  float* out = (float*)d_out;
  char* ws = (char*)d_ws;
  unsigned short* Xbq  = (unsigned short*)(ws);
  unsigned short* Xbkv = (unsigned short*)(ws + (1<<20));
  unsigned short* Wt4  = (unsigned short*)(ws + (2<<20));
  unsigned short* Wot  = (unsigned short*)(ws + (2<<20) + (512<<10));
  unsigned short* Qb   = (unsigned short*)(ws + (3<<20));
  unsigned short* Kb   = (unsigned short*)(ws + (4<<20));
  unsigned short* Vt   = (unsigned short*)(ws + (5<<20));
  unsigned short* Gg   = (unsigned short*)(ws + (6<<20));
  unsigned short* Og   = (unsigned short*)(ws + (7<<20));
  float*          Opart= (float*)(ws + (8<<20));        // 8 MB: [4][8][2048][32]
  float*          Mpart= (float*)(ws + (16<<20));       // 256 KB: [4][8][2048]
  float*          Lpart= (float*)(ws + (17<<20));       // 256 KB

  cvt_kernel<<<592, 256, 0, stream>>>(qx, kvx, Wq, Wk, Wv, Wg, Wo, Xbq, Xbkv, Wt4, Wot);
  dim3 gp(32, 16);
  proj_kernel<<<gp, 256, 0, stream>>>(Xbq, Xbkv, Wt4, Qb, Kb, Vt, Gg);
  attn_kernel<<<1024, 256, 0, stream>>>(Qb, Kb, Vt, bias, Opart, Mpart, Lpart);
  combine_kernel<<<256, 256, 0, stream>>>(Opart, Mpart, Lpart, Gg, Og);
  dim3 go(32, 4);
  oproj_kernel<<<go, 256, 0, stream>>>(Og, Wot, out);
}

// Round 6
// 60.909 us; speedup vs baseline: 1.1589x; 1.1589x over previous
//
#include <hip/hip_runtime.h>
#include <hip/hip_bf16.h>
#include <stdint.h>

typedef __attribute__((ext_vector_type(8))) short short8;
typedef __attribute__((ext_vector_type(8))) __bf16 bf16x8;
typedef __attribute__((ext_vector_type(4))) float f32x4;
typedef __attribute__((ext_vector_type(4))) float float4v;
typedef __attribute__((ext_vector_type(4))) unsigned short us4;
typedef unsigned int u32;
typedef __attribute__((address_space(3))) u32 lds_u32;
typedef const __attribute__((address_space(1))) u32 g_u32;

#define NSEQ 2048
#define L2E 1.44269504088896f

static __device__ __forceinline__ unsigned short f2bf(float x){
  union { float f; u32 u; } v; v.f = x;
  u32 r = v.u + 0x7fffu + ((v.u >> 16) & 1u);
  return (unsigned short)(r >> 16);
}
static __device__ __forceinline__ float bf2f(unsigned short s){
  union { float f; u32 u; } v; v.u = ((u32)s) << 16; return v.f;
}
static __device__ __forceinline__ void gload16(const void* g, void* l){
  __builtin_amdgcn_global_load_lds((g_u32*)g, (lds_u32*)l, 16, 0, 0);
}
static __device__ __forceinline__ f32x4 mfma16(bf16x8 a, bf16x8 b, f32x4 c){
  return __builtin_amdgcn_mfma_f32_16x16x32_bf16(a, b, c, 0, 0, 0);
}
static __device__ __forceinline__ bf16x8 ldfrag(const void* p){
  return *(const bf16x8*)p;
}
#define MEMFENCE() asm volatile("" ::: "memory")

// ---------------- kernel 1: convert inputs to bf16, transpose weights ----------------
__global__ __launch_bounds__(256) void cvt_kernel(const float* __restrict__ qx,
                           const float* __restrict__ kvx,
                           const float* __restrict__ Wq, const float* __restrict__ Wk,
                           const float* __restrict__ Wv, const float* __restrict__ Wg,
                           const float* __restrict__ Wo,
                           unsigned short* __restrict__ Xbq, unsigned short* __restrict__ Xbkv,
                           unsigned short* __restrict__ Wt4, unsigned short* __restrict__ Wot){
  __shared__ float T[64][65];
  int bid = blockIdx.x;
  if (bid < 512){
    int i4 = (bid*256 + threadIdx.x) * 4;
    float4v q = *(const float4v*)(qx + i4);
    float4v k = *(const float4v*)(kvx + i4);
    us4 qo, ko;
    #pragma unroll
    for (int j = 0; j < 4; ++j){ qo[j] = f2bf(q[j]); ko[j] = f2bf(k[j]); }
    *(us4*)(Xbq + i4) = qo;
    *(us4*)(Xbkv + i4) = ko;
  } else {
    int b2 = bid - 512;                     // 0..79
    int w = b2 >> 4, tile = b2 & 15, tr = tile >> 2, tc = tile & 3;
    const float* W = (w==0)?Wq:((w==1)?Wk:((w==2)?Wv:((w==3)?Wg:Wo)));
    int t = threadIdx.x;
    int rl = t >> 4, cq = t & 15;
    #pragma unroll
    for (int p = 0; p < 4; ++p){
      int r = p*16 + rl;
      float4v v = *(const float4v*)(W + (size_t)(tr*64 + r)*256 + tc*64 + cq*4);
      #pragma unroll
      for (int j = 0; j < 4; ++j) T[r][cq*4+j] = v[j];
    }
    __syncthreads();
    float s = (w==0) ? 0.17677669529663687f : 1.f;   // fold 1/sqrt(32) into Wq
    #pragma unroll
    for (int p = 0; p < 4; ++p){
      int o = p*16 + rl;
      us4 pk;
      #pragma unroll
      for (int j = 0; j < 4; ++j) pk[j] = f2bf(T[cq*4+j][o] * s);
      int og = tc*64 + o, ig = tr*64 + cq*4;
      if (w < 4) *(us4*)(Wt4 + (size_t)w*65536 + og*256 + ig) = pk;
      else       *(us4*)(Wot + (size_t)og*256 + ig) = pk;
    }
  }
}

// ---------------- kernel 2: fused QKVG projection GEMM ----------------
__global__ __launch_bounds__(256) void proj_kernel(const unsigned short* __restrict__ Xbq,
     const unsigned short* __restrict__ Xbkv, const unsigned short* __restrict__ Wt4,
     unsigned short* __restrict__ Qb, unsigned short* __restrict__ Kb,
     unsigned short* __restrict__ Vt, unsigned short* __restrict__ Gg){
  __shared__ unsigned short Asm[64*256];
  __shared__ unsigned short Bsm[64*256];
  int mt = blockIdx.x;            // 0..31
  int nt = blockIdx.y;            // 0..15
  int col0 = nt * 64;
  int w = col0 >> 8;              // 0=Q 1=K 2=V 3=G
  const unsigned short* A = (w==0 || w==3) ? Xbq : Xbkv;
  int tid = threadIdx.x, lane = tid & 63, wid = tid >> 6;
  const char* Ab = (const char*)A   + (size_t)mt*64*512;
  const char* Bb = (const char*)Wt4 + (size_t)col0*512;
  char* Asl = (char*)Asm; char* Bsl = (char*)Bsm;
  #pragma unroll
  for (int it = 0; it < 8; ++it){
    int o = it*4096 + wid*1024 + lane*16;
    int row = o >> 9, b = o & 511;
    int sb = (o & ~511) + (b ^ ((row & 15) << 4));
    gload16(Ab + sb, Asl + it*4096 + wid*1024);
    gload16(Bb + sb, Bsl + it*4096 + wid*1024);
  }
  __syncthreads();
  int ml = lane & 15, kg = lane >> 4;
  int m = wid*16 + ml;
  bf16x8 afr[8];
  #pragma unroll
  for (int ks = 0; ks < 8; ++ks)
    afr[ks] = ldfrag(Asl + m*512 + ((ks*64 + kg*16) ^ (ml << 4)));
  f32x4 acc[4];
  #pragma unroll
  for (int ct = 0; ct < 4; ++ct){
    acc[ct] = (f32x4){0.f,0.f,0.f,0.f};
    int oo = ct*16 + ml;
    #pragma unroll
    for (int ks = 0; ks < 8; ++ks){
      bf16x8 bfr = ldfrag(Bsl + oo*512 + ((ks*64 + kg*16) ^ (ml << 4)));
      acc[ct] = mfma16(afr[ks], bfr, acc[ct]);
    }
  }
  #pragma unroll
  for (int ct = 0; ct < 4; ++ct){
    int colg = col0 + ct*16 + ml;
    int cw = colg & 255, hh = cw >> 5, c = cw & 31;
    int n0 = mt*64 + wid*16 + kg*4;
    if (w == 2){
      us4 pk;
      pk[0]=f2bf(acc[ct][0]); pk[1]=f2bf(acc[ct][1]);
      pk[2]=f2bf(acc[ct][2]); pk[3]=f2bf(acc[ct][3]);
      *(us4*)((char*)Vt + ((size_t)(hh*32 + c)*NSEQ + n0)*2) = pk;
    } else {
      #pragma unroll
      for (int r = 0; r < 4; ++r){
        int n = n0 + r;
        float v = acc[ct][r];
        if (w == 0)      Qb[((size_t)hh*NSEQ + n)*32 + c] = f2bf(v);
        else if (w == 1) Kb[((size_t)hh*NSEQ + n)*32 + c] = f2bf(v);
        else             Gg[(size_t)n*256 + cw] = f2bf(1.f/(1.f + __expf(-v)));
      }
    }
  }
}

// ---------------- kernel 3: fused bias-attention, kv-split ----------------
// grid 1024 = 8 heads x 32 q-tiles(64) x 4 kv-chunks(512). 4 waves/block,
// 4 blocks/CU (LDS 40KB, occupancy LDS-limited — NO min-waves launch bound:
// round 5's (256,4) made hipcc cap VGPR at 64 and spill 78MB to scratch).
// Single-buffer bias regs bb[4][4] at FIFO distance 1: issued AFTER QK(t)
// consumed them (regs dead), BEFORE KV(t+2) staging. Queue at tile t+1:
// [KV(t+1), bias(t+1) x16, KV(t+2) x2] -> vmcnt(2) exact; no full drain
// anywhere except the last tile.
__global__ __launch_bounds__(256) void attn_kernel(const unsigned short* __restrict__ Qb,
    const unsigned short* __restrict__ Kb, const unsigned short* __restrict__ Vt,
    const float* __restrict__ bias,
    float* __restrict__ Opart, float* __restrict__ Mpart, float* __restrict__ Lpart){
  __shared__ unsigned short Ksm[4][2048];   // [64 kv][32 c] bf16, 4 bufs
  __shared__ unsigned short Vsm[4][2048];   // [32 c][64 kv] bf16, 4 bufs
  __shared__ unsigned short Psm[4096];      // [64 q][64 kv] bf16 (wave-local rows)
  int bid = blockIdx.x;
  int h = bid >> 7, qt = (bid >> 2) & 31, ch = bid & 3;
  int q0 = qt * 64;
  int tid = threadIdx.x, lane = tid & 63, wid = tid >> 6;
  int ml = lane & 15, kg = lane >> 4;
  int qw = q0 + wid*16;
  bf16x8 qfr = ldfrag((const char*)Qb + (((size_t)h*NSEQ + qw + ml)*32 + kg*8)*2);
  const char* Kbase = (const char*)Kb + (size_t)h*NSEQ*32*2;
  const char* Vbase = (const char*)Vt + (size_t)h*32*NSEQ*2;
  const float* bias_l = bias + (size_t)h*NSEQ*NSEQ + (size_t)(qw + kg*4)*NSEQ + ch*512 + ml;
  const float* br0 = bias_l;
  const float* br1 = bias_l + NSEQ;
  const float* br2 = bias_l + 2*NSEQ;
  const float* br3 = bias_l + 3*NSEQ;
  float mreg[4] = {-3e38f,-3e38f,-3e38f,-3e38f};
  float lreg[4] = {0.f,0.f,0.f,0.f};
  f32x4 oacc[2];
  oacc[0] = (f32x4){0.f,0.f,0.f,0.f};
  oacc[1] = (f32x4){0.f,0.f,0.f,0.f};

  auto stage = [&](int t, int buf){   // t = tile within chunk (0..7)
    int tg = ch*8 + t;                // global 64-kv tile
    int o = tid*16;
    int n = o >> 6, kb = o & 63;
    gload16(Kbase + (size_t)tg*4096 + (o & ~63) + (kb ^ (((n>>1)&3) << 4)),
            (char*)&Ksm[buf][0] + o);
    int c = o >> 7, vb = o & 127;
    gload16(Vbase + (size_t)c*4096 + (size_t)tg*128 + (vb ^ ((c&7) << 4)),
            (char*)&Vsm[buf][0] + o);
  };

  float bb[4][4];
  // prologue, FIFO order: bias(0) first (oldest), then KV(0), KV(1)
  #pragma unroll
  for (int ct = 0; ct < 4; ++ct){
    bb[ct][0] = br0[ct*16];
    bb[ct][1] = br1[ct*16];
    bb[ct][2] = br2[ct*16];
    bb[ct][3] = br3[ct*16];
  }
  MEMFENCE();
  stage(0, 0);
  stage(1, 1);
  for (int t = 0; t < 8; ++t){
    int cur = t & 3;
    // forces bias(t)+KV(t) landed; leaves exactly KV(t+1) (2 loads) in flight.
    if (t == 7) asm volatile("s_waitcnt vmcnt(0)" ::: "memory");
    else        asm volatile("s_waitcnt vmcnt(2)" ::: "memory");
    __builtin_amdgcn_s_barrier();
    MEMFENCE();
    // S = bias(t) [regs landed one tile ago] + Q K^T
    f32x4 s[4];
    #pragma unroll
    for (int ct = 0; ct < 4; ++ct){
      f32x4 b;
      #pragma unroll
      for (int r = 0; r < 4; ++r) b[r] = bb[ct][r];
      int n = ct*16 + ml;
      bf16x8 kfr = ldfrag((char*)&Ksm[cur][0] + n*64 + ((kg*16) ^ (((n>>1)&3) << 4)));
      s[ct] = mfma16(qfr, kfr, b);
    }
    MEMFENCE();
    // bb regs now dead -> issue bias(t+1) into them (FIFO pos: before KV(t+2))
    if (t < 7){
      int off = (t+1)*64;
      #pragma unroll
      for (int ct = 0; ct < 4; ++ct){
        bb[ct][0] = br0[off + ct*16];
        bb[ct][1] = br1[off + ct*16];
        bb[ct][2] = br2[off + ct*16];
        bb[ct][3] = br3[off + ct*16];
      }
    }
    MEMFENCE();
    if (t < 6) stage(t+2, (t+2) & 3);   // WAR-safe: 2 barriers since last read
    MEMFENCE();
    // online softmax (16 rows/wave; row r lives across 16 ml lanes)
    float mx[4];
    #pragma unroll
    for (int r = 0; r < 4; ++r){
      mx[r] = fmaxf(fmaxf(s[0][r], s[1][r]), fmaxf(s[2][r], s[3][r]));
    }
    #pragma unroll
    for (int d = 1; d < 16; d <<= 1){
      #pragma unroll
      for (int r = 0; r < 4; ++r) mx[r] = fmaxf(mx[r], __shfl_xor(mx[r], d));
    }
    float sc[4], rs[4];
    #pragma unroll
    for (int r = 0; r < 4; ++r){
      float mn = fmaxf(mreg[r], mx[r]);
      sc[r] = exp2f((mreg[r] - mn) * L2E);
      mreg[r] = mn;
      rs[r] = 0.f;
    }
    #pragma unroll
    for (int ct = 0; ct < 4; ++ct){
      #pragma unroll
      for (int r = 0; r < 4; ++r){
        float pv = exp2f((s[ct][r] - mreg[r]) * L2E);
        s[ct][r] = pv;
        rs[r] += pv;
      }
    }
    #pragma unroll
    for (int d = 1; d < 16; d <<= 1){
      #pragma unroll
      for (int r = 0; r < 4; ++r) rs[r] += __shfl_xor(rs[r], d);
    }
    #pragma unroll
    for (int r = 0; r < 4; ++r) lreg[r] = lreg[r]*sc[r] + rs[r];
    #pragma unroll
    for (int c2 = 0; c2 < 2; ++c2){
      #pragma unroll
      for (int r = 0; r < 4; ++r) oacc[c2][r] *= sc[r];
    }
    // P -> LDS (wave-local rows; same-wave write->read, lgkmcnt-ordered)
    #pragma unroll
    for (int ct = 0; ct < 4; ++ct){
      #pragma unroll
      for (int r = 0; r < 4; ++r){
        int q = wid*16 + kg*4 + r;
        int k = ct*16 + ml;
        *(unsigned short*)((char*)Psm + q*128 + ((k*2) ^ ((q&7) << 4))) = f2bf(s[ct][r]);
      }
    }
    // O += P V
    int qq = wid*16 + ml;
    #pragma unroll
    for (int ks = 0; ks < 2; ++ks){
      bf16x8 pfr = ldfrag((char*)Psm + qq*128 + ((ks*64 + kg*16) ^ ((qq&7) << 4)));
      #pragma unroll
      for (int c2 = 0; c2 < 2; ++c2){
        int c = c2*16 + ml;
        bf16x8 vfr = ldfrag((char*)&Vsm[cur][0] + c*128 + ((ks*64 + kg*16) ^ ((c&7) << 4)));
        oacc[c2] = mfma16(pfr, vfr, oacc[c2]);
      }
    }
    MEMFENCE();
  }
  // epilogue: partial results (unnormalized O, running m, running l)
  size_t pbase = ((size_t)(ch*8 + h)*NSEQ);
  #pragma unroll
  for (int c2 = 0; c2 < 2; ++c2){
    #pragma unroll
    for (int r = 0; r < 4; ++r){
      int q = qw + kg*4 + r;
      Opart[(pbase + q)*32 + c2*16 + ml] = oacc[c2][r];
    }
  }
  if (ml == 0){
    #pragma unroll
    for (int r = 0; r < 4; ++r){
      int q = qw + kg*4 + r;
      Mpart[pbase + q] = mreg[r];
      Lpart[pbase + q] = lreg[r];
    }
  }
}

// ---------------- kernel 3b: combine kv-chunks + gate ----------------
__global__ __launch_bounds__(256) void combine_kernel(const float* __restrict__ Opart,
    const float* __restrict__ Mpart, const float* __restrict__ Lpart,
    const unsigned short* __restrict__ Gg, unsigned short* __restrict__ Og){
  int n = blockIdx.x*8 + (threadIdx.x >> 5);
  int c = threadIdx.x & 31;
  #pragma unroll
  for (int h = 0; h < 8; ++h){
    float m0 = Mpart[(size_t)(0*8+h)*NSEQ + n], m1 = Mpart[(size_t)(1*8+h)*NSEQ + n];
    float m2 = Mpart[(size_t)(2*8+h)*NSEQ + n], m3 = Mpart[(size_t)(3*8+h)*NSEQ + n];
    float M = fmaxf(fmaxf(m0, m1), fmaxf(m2, m3));
    float e0 = exp2f((m0-M)*L2E), e1 = exp2f((m1-M)*L2E);
    float e2 = exp2f((m2-M)*L2E), e3 = exp2f((m3-M)*L2E);
    float L = Lpart[(size_t)(0*8+h)*NSEQ + n]*e0 + Lpart[(size_t)(1*8+h)*NSEQ + n]*e1
            + Lpart[(size_t)(2*8+h)*NSEQ + n]*e2 + Lpart[(size_t)(3*8+h)*NSEQ + n]*e3;
    float o = Opart[((size_t)(0*8+h)*NSEQ + n)*32 + c]*e0
            + Opart[((size_t)(1*8+h)*NSEQ + n)*32 + c]*e1
            + Opart[((size_t)(2*8+h)*NSEQ + n)*32 + c]*e2
            + Opart[((size_t)(3*8+h)*NSEQ + n)*32 + c]*e3;
    float g = bf2f(Gg[(size_t)n*256 + h*32 + c]);
    Og[(size_t)n*256 + h*32 + c] = f2bf(o / L * g);
  }
}

// ---------------- kernel 4: output projection ----------------
__global__ __launch_bounds__(256) void oproj_kernel(const unsigned short* __restrict__ Og,
    const unsigned short* __restrict__ Wot, float* __restrict__ out){
  __shared__ unsigned short Asm[64*256];
  __shared__ unsigned short Bsm[64*256];
  int mt = blockIdx.x, nt = blockIdx.y;
  int col0 = nt * 64;
  int tid = threadIdx.x, lane = tid & 63, wid = tid >> 6;
  const char* Ab = (const char*)Og  + (size_t)mt*64*512;
  const char* Bb = (const char*)Wot + (size_t)col0*512;
  char* Asl = (char*)Asm; char* Bsl = (char*)Bsm;
  #pragma unroll
  for (int it = 0; it < 8; ++it){
    int o = it*4096 + wid*1024 + lane*16;
    int row = o >> 9, b = o & 511;
    int sb = (o & ~511) + (b ^ ((row & 15) << 4));
    gload16(Ab + sb, Asl + it*4096 + wid*1024);
    gload16(Bb + sb, Bsl + it*4096 + wid*1024);
  }
  __syncthreads();
  int ml = lane & 15, kg = lane >> 4;
  int m = wid*16 + ml;
  bf16x8 afr[8];
  #pragma unroll
  for (int ks = 0; ks < 8; ++ks)
    afr[ks] = ldfrag(Asl + m*512 + ((ks*64 + kg*16) ^ (ml << 4)));
  f32x4 acc[4];
  #pragma unroll
  for (int ct = 0; ct < 4; ++ct){
    acc[ct] = (f32x4){0.f,0.f,0.f,0.f};
    int oo = ct*16 + ml;
    #pragma unroll
    for (int ks = 0; ks < 8; ++ks){
      bf16x8 bfr = ldfrag(Bsl + oo*512 + ((ks*64 + kg*16) ^ (ml << 4)));
      acc[ct] = mfma16(afr[ks], bfr, acc[ct]);
    }
  }
  #pragma unroll
  for (int ct = 0; ct < 4; ++ct){
    #pragma unroll
    for (int r = 0; r < 4; ++r){
      int mm = mt*64 + wid*16 + kg*4 + r;
      out[(size_t)mm*256 + col0 + ct*16 + ml] = acc[ct][r];
    }
  }
}

extern "C" void kernel_launch(void* const* d_in, const int* in_sizes, int n_in,
                              void* d_out, int out_size, void* d_ws, size_t ws_size,
                              hipStream_t stream) {
  const float* qx   = (const float*)d_in[0];
  const float* kvx  = (const float*)d_in[1];
  const float* bias = (const float*)d_in[2];
  const float* Wq   = (const float*)d_in[3];
  const float* Wk   = (const float*)d_in[4];
  const float* Wv   = (const float*)d_in[5];
  const float* Wg   = (const float*)d_in[6];
  const float* Wo   = (const float*)d_in[7];
  float* out = (float*)d_out;
  char* ws = (char*)d_ws;
  unsigned short* Xbq  = (unsigned short*)(ws);
  unsigned short* Xbkv = (unsigned short*)(ws + (1<<20));
  unsigned short* Wt4  = (unsigned short*)(ws + (2<<20));
  unsigned short* Wot  = (unsigned short*)(ws + (2<<20) + (512<<10));
  unsigned short* Qb   = (unsigned short*)(ws + (3<<20));
  unsigned short* Kb   = (unsigned short*)(ws + (4<<20));
  unsigned short* Vt   = (unsigned short*)(ws + (5<<20));
  unsigned short* Gg   = (unsigned short*)(ws + (6<<20));
  unsigned short* Og   = (unsigned short*)(ws + (7<<20));
  float*          Opart= (float*)(ws + (8<<20));        // 8 MB: [4][8][2048][32]
  float*          Mpart= (float*)(ws + (16<<20));       // 256 KB: [4][8][2048]
  float*          Lpart= (float*)(ws + (17<<20));       // 256 KB

  cvt_kernel<<<592, 256, 0, stream>>>(qx, kvx, Wq, Wk, Wv, Wg, Wo, Xbq, Xbkv, Wt4, Wot);
  dim3 gp(32, 16);
  proj_kernel<<<gp, 256, 0, stream>>>(Xbq, Xbkv, Wt4, Qb, Kb, Vt, Gg);
  attn_kernel<<<1024, 256, 0, stream>>>(Qb, Kb, Vt, bias, Opart, Mpart, Lpart);
  combine_kernel<<<256, 256, 0, stream>>>(Opart, Mpart, Lpart, Gg, Og);
  dim3 go(32, 4);
  oproj_kernel<<<go, 256, 0, stream>>>(Og, Wot, out);
}

// Round 7
// 50.825 us; speedup vs baseline: 1.3888x; 1.1984x over previous
//
#include <hip/hip_runtime.h>
#include <hip/hip_bf16.h>
#include <stdint.h>

typedef __attribute__((ext_vector_type(8))) short short8;
typedef __attribute__((ext_vector_type(8))) __bf16 bf16x8;
typedef __attribute__((ext_vector_type(4))) float f32x4;
typedef __attribute__((ext_vector_type(4))) float float4v;
typedef __attribute__((ext_vector_type(4))) unsigned short us4;
typedef unsigned int u32;
typedef __attribute__((ext_vector_type(2))) u32 u32x2;
typedef __attribute__((address_space(3))) u32 lds_u32;
typedef const __attribute__((address_space(1))) u32 g_u32;

#define NSEQ 2048
#define L2E 1.44269504088896f

static __device__ __forceinline__ unsigned short f2bf(float x){
  union { float f; u32 u; } v; v.f = x;
  u32 r = v.u + 0x7fffu + ((v.u >> 16) & 1u);
  return (unsigned short)(r >> 16);
}
static __device__ __forceinline__ float bf2f(unsigned short s){
  union { float f; u32 u; } v; v.u = ((u32)s) << 16; return v.f;
}
static __device__ __forceinline__ u32 cvtpk(float lo, float hi){
  u32 r; asm("v_cvt_pk_bf16_f32 %0, %1, %2" : "=v"(r) : "v"(lo), "v"(hi)); return r;
}
static __device__ __forceinline__ void gload16(const void* g, void* l){
  __builtin_amdgcn_global_load_lds((g_u32*)g, (lds_u32*)l, 16, 0, 0);
}
static __device__ __forceinline__ f32x4 mfma16(bf16x8 a, bf16x8 b, f32x4 c){
  return __builtin_amdgcn_mfma_f32_16x16x32_bf16(a, b, c, 0, 0, 0);
}
static __device__ __forceinline__ bf16x8 ldfrag(const void* p){
  return *(const bf16x8*)p;
}
#define MEMFENCE() asm volatile("" ::: "memory")

// ---------------- kernel 1: convert inputs to bf16, transpose weights ----------------
__global__ __launch_bounds__(256) void cvt_kernel(const float* __restrict__ qx,
                           const float* __restrict__ kvx,
                           const float* __restrict__ Wq, const float* __restrict__ Wk,
                           const float* __restrict__ Wv, const float* __restrict__ Wg,
                           const float* __restrict__ Wo,
                           unsigned short* __restrict__ Xbq, unsigned short* __restrict__ Xbkv,
                           unsigned short* __restrict__ Wt4, unsigned short* __restrict__ Wot){
  __shared__ float T[64][65];
  int bid = blockIdx.x;
  if (bid < 512){
    int i4 = (bid*256 + threadIdx.x) * 4;
    float4v q = *(const float4v*)(qx + i4);
    float4v k = *(const float4v*)(kvx + i4);
    us4 qo, ko;
    #pragma unroll
    for (int j = 0; j < 4; ++j){ qo[j] = f2bf(q[j]); ko[j] = f2bf(k[j]); }
    *(us4*)(Xbq + i4) = qo;
    *(us4*)(Xbkv + i4) = ko;
  } else {
    int b2 = bid - 512;                     // 0..79
    int w = b2 >> 4, tile = b2 & 15, tr = tile >> 2, tc = tile & 3;
    const float* W = (w==0)?Wq:((w==1)?Wk:((w==2)?Wv:((w==3)?Wg:Wo)));
    int t = threadIdx.x;
    int rl = t >> 4, cq = t & 15;
    #pragma unroll
    for (int p = 0; p < 4; ++p){
      int r = p*16 + rl;
      float4v v = *(const float4v*)(W + (size_t)(tr*64 + r)*256 + tc*64 + cq*4);
      #pragma unroll
      for (int j = 0; j < 4; ++j) T[r][cq*4+j] = v[j];
    }
    __syncthreads();
    float s = (w==0) ? 0.17677669529663687f : 1.f;   // fold 1/sqrt(32) into Wq
    #pragma unroll
    for (int p = 0; p < 4; ++p){
      int o = p*16 + rl;
      us4 pk;
      #pragma unroll
      for (int j = 0; j < 4; ++j) pk[j] = f2bf(T[cq*4+j][o] * s);
      int og = tc*64 + o, ig = tr*64 + cq*4;
      if (w < 4) *(us4*)(Wt4 + (size_t)w*65536 + og*256 + ig) = pk;
      else       *(us4*)(Wot + (size_t)og*256 + ig) = pk;
    }
  }
}

// ---------------- kernel 2: fused QKVG projection GEMM ----------------
__global__ __launch_bounds__(256) void proj_kernel(const unsigned short* __restrict__ Xbq,
     const unsigned short* __restrict__ Xbkv, const unsigned short* __restrict__ Wt4,
     unsigned short* __restrict__ Qb, unsigned short* __restrict__ Kb,
     unsigned short* __restrict__ Vt, unsigned short* __restrict__ Gg){
  __shared__ unsigned short Asm[64*256];
  __shared__ unsigned short Bsm[64*256];
  int mt = blockIdx.x;            // 0..31
  int nt = blockIdx.y;            // 0..15
  int col0 = nt * 64;
  int w = col0 >> 8;              // 0=Q 1=K 2=V 3=G
  const unsigned short* A = (w==0 || w==3) ? Xbq : Xbkv;
  int tid = threadIdx.x, lane = tid & 63, wid = tid >> 6;
  const char* Ab = (const char*)A   + (size_t)mt*64*512;
  const char* Bb = (const char*)Wt4 + (size_t)col0*512;
  char* Asl = (char*)Asm; char* Bsl = (char*)Bsm;
  #pragma unroll
  for (int it = 0; it < 8; ++it){
    int o = it*4096 + wid*1024 + lane*16;
    int row = o >> 9, b = o & 511;
    int sb = (o & ~511) + (b ^ ((row & 15) << 4));
    gload16(Ab + sb, Asl + it*4096 + wid*1024);
    gload16(Bb + sb, Bsl + it*4096 + wid*1024);
  }
  __syncthreads();
  int ml = lane & 15, kg = lane >> 4;
  int m = wid*16 + ml;
  bf16x8 afr[8];
  #pragma unroll
  for (int ks = 0; ks < 8; ++ks)
    afr[ks] = ldfrag(Asl + m*512 + ((ks*64 + kg*16) ^ (ml << 4)));
  f32x4 acc[4];
  #pragma unroll
  for (int ct = 0; ct < 4; ++ct){
    acc[ct] = (f32x4){0.f,0.f,0.f,0.f};
    int oo = ct*16 + ml;
    #pragma unroll
    for (int ks = 0; ks < 8; ++ks){
      bf16x8 bfr = ldfrag(Bsl + oo*512 + ((ks*64 + kg*16) ^ (ml << 4)));
      acc[ct] = mfma16(afr[ks], bfr, acc[ct]);
    }
  }
  #pragma unroll
  for (int ct = 0; ct < 4; ++ct){
    int colg = col0 + ct*16 + ml;
    int cw = colg & 255, hh = cw >> 5, c = cw & 31;
    int n0 = mt*64 + wid*16 + kg*4;
    if (w == 2){
      us4 pk;
      pk[0]=f2bf(acc[ct][0]); pk[1]=f2bf(acc[ct][1]);
      pk[2]=f2bf(acc[ct][2]); pk[3]=f2bf(acc[ct][3]);
      *(us4*)((char*)Vt + ((size_t)(hh*32 + c)*NSEQ + n0)*2) = pk;
    } else {
      #pragma unroll
      for (int r = 0; r < 4; ++r){
        int n = n0 + r;
        float v = acc[ct][r];
        if (w == 0)      Qb[((size_t)hh*NSEQ + n)*32 + c] = f2bf(v);
        else if (w == 1) Kb[((size_t)hh*NSEQ + n)*32 + c] = f2bf(v);
        else             Gg[(size_t)n*256 + cw] = f2bf(1.f/(1.f + __expf(-v)));
      }
    }
  }
}

// ---------------- kernel 3: fused bias-attention, kv-split, SWAPPED QK^T ----------------
// grid 1024 = 8 heads x 32 q-tiles(64) x 4 kv-chunks(512). 4 waves/block,
// 4 blocks/CU (LDS 40KB). S^T = mfma(K, Q): C-fragment element (lane ml,kg; reg r)
// = S[q = qw+ml][k = ct*16+kg*4+r], so:
//  - bias fragment = ONE float4/lane/quadrant (4 coalesced wide loads/tile, was 16 dwords)
//  - softmax row q=ml: in-lane 16-val reduce + 2 shuffles (was 16 shuffles/reduce)
//  - P pack: r=0..3 -> cvt_pk x2 + one ds_write_b64 per quadrant (was 16 scalar writes)
// K/Q/V fragment loads are unchanged (same layouts serve swapped A/B roles).
// Counted-vmcnt pipeline: queue/tile = [KV(t+1):2][bias(t+1):4][KV(t+2):2] -> vmcnt(2).
__global__ __launch_bounds__(256) void attn_kernel(const unsigned short* __restrict__ Qb,
    const unsigned short* __restrict__ Kb, const unsigned short* __restrict__ Vt,
    const float* __restrict__ bias,
    float* __restrict__ Opart, float* __restrict__ Mpart, float* __restrict__ Lpart){
  __shared__ unsigned short Ksm[4][2048];   // [64 kv][32 c] bf16, 4 bufs
  __shared__ unsigned short Vsm[4][2048];   // [32 c][64 kv] bf16, 4 bufs
  __shared__ unsigned short Psm[4096];      // [64 q][64 kv] bf16 (wave-local rows)
  int bid = blockIdx.x;
  int h = bid >> 7, qt = (bid >> 2) & 31, ch = bid & 3;
  int q0 = qt * 64;
  int tid = threadIdx.x, lane = tid & 63, wid = tid >> 6;
  int ml = lane & 15, kg = lane >> 4;
  int qw = q0 + wid*16;
  bf16x8 qfr = ldfrag((const char*)Qb + (((size_t)h*NSEQ + qw + ml)*32 + kg*8)*2);
  const char* Kbase = (const char*)Kb + (size_t)h*NSEQ*32*2;
  const char* Vbase = (const char*)Vt + (size_t)h*32*NSEQ*2;
  // lane-private bias base: row (qw+ml), col = chunk start + kg*4 (+t*64 + ct*16)
  const float* bias_q = bias + (size_t)h*NSEQ*NSEQ + (size_t)(qw + ml)*NSEQ + ch*512 + kg*4;
  float mreg = -3e38f;     // running max for q = qw+ml (dup over kg)
  float lreg = 0.f;        // running sum
  f32x4 oacc[2];
  oacc[0] = (f32x4){0.f,0.f,0.f,0.f};
  oacc[1] = (f32x4){0.f,0.f,0.f,0.f};

  auto stage = [&](int t, int buf){   // t = tile within chunk (0..7)
    int tg = ch*8 + t;                // global 64-kv tile
    int o = tid*16;
    int n = o >> 6, kb = o & 63;
    gload16(Kbase + (size_t)tg*4096 + (o & ~63) + (kb ^ (((n>>1)&3) << 4)),
            (char*)&Ksm[buf][0] + o);
    int c = o >> 7, vb = o & 127;
    gload16(Vbase + (size_t)c*4096 + (size_t)tg*128 + (vb ^ ((c&7) << 4)),
            (char*)&Vsm[buf][0] + o);
  };

  float4v bb[4];
  // prologue, FIFO order: bias(0) first (oldest), then KV(0), KV(1)
  #pragma unroll
  for (int ct = 0; ct < 4; ++ct) bb[ct] = *(const float4v*)(bias_q + ct*16);
  MEMFENCE();
  stage(0, 0);
  stage(1, 1);
  int qrow = wid*16 + ml;
  char* Pb = (char*)Psm + qrow*128;
  int qs = (ml & 7) << 4;
  for (int t = 0; t < 8; ++t){
    int cur = t & 3;
    // forces bias(t)+KV(t) landed; leaves exactly KV(t+1) (2 loads) in flight.
    if (t == 7) asm volatile("s_waitcnt vmcnt(0)" ::: "memory");
    else        asm volatile("s_waitcnt vmcnt(2)" ::: "memory");
    __builtin_amdgcn_s_barrier();
    MEMFENCE();
    // S^T = mfma(K, Q) with bias as C-init; s[ct][r] = S[qw+ml][ct*16+kg*4+r]
    f32x4 s[4];
    #pragma unroll
    for (int ct = 0; ct < 4; ++ct){
      int n = ct*16 + ml;
      bf16x8 kfr = ldfrag((char*)&Ksm[cur][0] + n*64 + ((kg*16) ^ (((n>>1)&3) << 4)));
      f32x4 b;
      #pragma unroll
      for (int r = 0; r < 4; ++r) b[r] = bb[ct][r];
      s[ct] = mfma16(kfr, qfr, b);
    }
    MEMFENCE();
    // bb regs dead -> issue bias(t+1) (FIFO pos: before KV(t+2))
    if (t < 7){
      #pragma unroll
      for (int ct = 0; ct < 4; ++ct)
        bb[ct] = *(const float4v*)(bias_q + (t+1)*64 + ct*16);
    }
    MEMFENCE();
    if (t < 6) stage(t+2, (t+2) & 3);   // WAR-safe: distance-4 bufs, 1 barrier/tile
    MEMFENCE();
    // online softmax for row q=ml: in-lane 16-val tree + xor16/xor32
    float m0 = fmaxf(fmaxf(s[0][0],s[0][1]), fmaxf(s[0][2],s[0][3]));
    float m1 = fmaxf(fmaxf(s[1][0],s[1][1]), fmaxf(s[1][2],s[1][3]));
    float m2 = fmaxf(fmaxf(s[2][0],s[2][1]), fmaxf(s[2][2],s[2][3]));
    float m3 = fmaxf(fmaxf(s[3][0],s[3][1]), fmaxf(s[3][2],s[3][3]));
    float mx = fmaxf(fmaxf(m0,m1), fmaxf(m2,m3));
    mx = fmaxf(mx, __shfl_xor(mx, 16));
    mx = fmaxf(mx, __shfl_xor(mx, 32));
    float mn = fmaxf(mreg, mx);
    float sc = exp2f((mreg - mn) * L2E);
    mreg = mn;
    float rs = 0.f;
    #pragma unroll
    for (int ct = 0; ct < 4; ++ct){
      #pragma unroll
      for (int r = 0; r < 4; ++r){
        float pv = exp2f((s[ct][r] - mn) * L2E);
        s[ct][r] = pv;
        rs += pv;
      }
    }
    rs += __shfl_xor(rs, 16);
    rs += __shfl_xor(rs, 32);
    lreg = lreg*sc + rs;
    // relocate rescale factor to PV layout (oacc row q = kg*4+r lives at lane ml=q)
    float scq[4];
    #pragma unroll
    for (int r = 0; r < 4; ++r) scq[r] = __shfl(sc, kg*4 + r);
    #pragma unroll
    for (int c2 = 0; c2 < 2; ++c2){
      #pragma unroll
      for (int r = 0; r < 4; ++r) oacc[c2][r] *= scq[r];
    }
    // P -> LDS: one b64 (4 bf16, r=0..3) per quadrant, 16B-block XOR swizzle
    #pragma unroll
    for (int ct = 0; ct < 4; ++ct){
      u32x2 pk;
      pk[0] = cvtpk(s[ct][0], s[ct][1]);
      pk[1] = cvtpk(s[ct][2], s[ct][3]);
      *(u32x2*)(Pb + ((ct*32 + kg*8) ^ qs)) = pk;
    }
    // O += P V  (A-frag: P rows q; B-frag: V^T rows c — unchanged)
    #pragma unroll
    for (int ks = 0; ks < 2; ++ks){
      bf16x8 pfr = ldfrag(Pb + ((ks*64 + kg*16) ^ qs));
      #pragma unroll
      for (int c2 = 0; c2 < 2; ++c2){
        int c = c2*16 + ml;
        bf16x8 vfr = ldfrag((char*)&Vsm[cur][0] + c*128 + ((ks*64 + kg*16) ^ ((c&7) << 4)));
        oacc[c2] = mfma16(pfr, vfr, oacc[c2]);
      }
    }
    MEMFENCE();
  }
  // epilogue: softmax state lives at lanes kg==0 (16 consecutive q rows)
  size_t pbase = ((size_t)(ch*8 + h)*NSEQ);
  if (kg == 0){
    Mpart[pbase + qw + ml] = mreg;
    Lpart[pbase + qw + ml] = lreg;
  }
  #pragma unroll
  for (int c2 = 0; c2 < 2; ++c2){
    #pragma unroll
    for (int r = 0; r < 4; ++r){
      int q = qw + kg*4 + r;
      Opart[(pbase + q)*32 + c2*16 + ml] = oacc[c2][r];
    }
  }
}

// ---------------- kernel 3b: combine kv-chunks + gate ----------------
__global__ __launch_bounds__(256) void combine_kernel(const float* __restrict__ Opart,
    const float* __restrict__ Mpart, const float* __restrict__ Lpart,
    const unsigned short* __restrict__ Gg, unsigned short* __restrict__ Og){
  int n = blockIdx.x*8 + (threadIdx.x >> 5);
  int c = threadIdx.x & 31;
  #pragma unroll
  for (int h = 0; h < 8; ++h){
    float m0 = Mpart[(size_t)(0*8+h)*NSEQ + n], m1 = Mpart[(size_t)(1*8+h)*NSEQ + n];
    float m2 = Mpart[(size_t)(2*8+h)*NSEQ + n], m3 = Mpart[(size_t)(3*8+h)*NSEQ + n];
    float M = fmaxf(fmaxf(m0, m1), fmaxf(m2, m3));
    float e0 = exp2f((m0-M)*L2E), e1 = exp2f((m1-M)*L2E);
    float e2 = exp2f((m2-M)*L2E), e3 = exp2f((m3-M)*L2E);
    float L = Lpart[(size_t)(0*8+h)*NSEQ + n]*e0 + Lpart[(size_t)(1*8+h)*NSEQ + n]*e1
            + Lpart[(size_t)(2*8+h)*NSEQ + n]*e2 + Lpart[(size_t)(3*8+h)*NSEQ + n]*e3;
    float o = Opart[((size_t)(0*8+h)*NSEQ + n)*32 + c]*e0
            + Opart[((size_t)(1*8+h)*NSEQ + n)*32 + c]*e1
            + Opart[((size_t)(2*8+h)*NSEQ + n)*32 + c]*e2
            + Opart[((size_t)(3*8+h)*NSEQ + n)*32 + c]*e3;
    float g = bf2f(Gg[(size_t)n*256 + h*32 + c]);
    Og[(size_t)n*256 + h*32 + c] = f2bf(o / L * g);
  }
}

// ---------------- kernel 4: output projection ----------------
__global__ __launch_bounds__(256) void oproj_kernel(const unsigned short* __restrict__ Og,
    const unsigned short* __restrict__ Wot, float* __restrict__ out){
  __shared__ unsigned short Asm[64*256];
  __shared__ unsigned short Bsm[64*256];
  int mt = blockIdx.x, nt = blockIdx.y;
  int col0 = nt * 64;
  int tid = threadIdx.x, lane = tid & 63, wid = tid >> 6;
  const char* Ab = (const char*)Og  + (size_t)mt*64*512;
  const char* Bb = (const char*)Wot + (size_t)col0*512;
  char* Asl = (char*)Asm; char* Bsl = (char*)Bsm;
  #pragma unroll
  for (int it = 0; it < 8; ++it){
    int o = it*4096 + wid*1024 + lane*16;
    int row = o >> 9, b = o & 511;
    int sb = (o & ~511) + (b ^ ((row & 15) << 4));
    gload16(Ab + sb, Asl + it*4096 + wid*1024);
    gload16(Bb + sb, Bsl + it*4096 + wid*1024);
  }
  __syncthreads();
  int ml = lane & 15, kg = lane >> 4;
  int m = wid*16 + ml;
  bf16x8 afr[8];
  #pragma unroll
  for (int ks = 0; ks < 8; ++ks)
    afr[ks] = ldfrag(Asl + m*512 + ((ks*64 + kg*16) ^ (ml << 4)));
  f32x4 acc[4];
  #pragma unroll
  for (int ct = 0; ct < 4; ++ct){
    acc[ct] = (f32x4){0.f,0.f,0.f,0.f};
    int oo = ct*16 + ml;
    #pragma unroll
    for (int ks = 0; ks < 8; ++ks){
      bf16x8 bfr = ldfrag(Bsl + oo*512 + ((ks*64 + kg*16) ^ (ml << 4)));
      acc[ct] = mfma16(afr[ks], bfr, acc[ct]);
    }
  }
  #pragma unroll
  for (int ct = 0; ct < 4; ++ct){
    #pragma unroll
    for (int r = 0; r < 4; ++r){
      int mm = mt*64 + wid*16 + kg*4 + r;
      out[(size_t)mm*256 + col0 + ct*16 + ml] = acc[ct][r];
    }
  }
}

extern "C" void kernel_launch(void* const* d_in, const int* in_sizes, int n_in,
                              void* d_out, int out_size, void* d_ws, size_t ws_size,
                              hipStream_t stream) {
  const float* qx   = (const float*)d_in[0];
  const float* kvx  = (const float*)d_in[1];
  const float* bias = (const float*)d_in[2];
  const float* Wq   = (const float*)d_in[3];
  const float* Wk   = (const float*)d_in[4];
  const float* Wv   = (const float*)d_in[5];
  const float* Wg   = (const float*)d_in[6];
  const float* Wo   = (const float*)d_in[7];
  float* out = (float*)d_out;
  char* ws = (char*)d_ws;
  unsigned short* Xbq  = (unsigned short*)(ws);
  unsigned short* Xbkv = (unsigned short*)(ws + (1<<20));
  unsigned short* Wt4  = (unsigned short*)(ws + (2<<20));
  unsigned short* Wot  = (unsigned short*)(ws + (2<<20) + (512<<10));
  unsigned short* Qb   = (unsigned short*)(ws + (3<<20));
  unsigned short* Kb   = (unsigned short*)(ws + (4<<20));
  unsigned short* Vt   = (unsigned short*)(ws + (5<<20));
  unsigned short* Gg   = (unsigned short*)(ws + (6<<20));
  unsigned short* Og   = (unsigned short*)(ws + (7<<20));
  float*          Opart= (float*)(ws + (8<<20));        // 8 MB: [4][8][2048][32]
  float*          Mpart= (float*)(ws + (16<<20));       // 256 KB: [4][8][2048]
  float*          Lpart= (float*)(ws + (17<<20));       // 256 KB

  cvt_kernel<<<592, 256, 0, stream>>>(qx, kvx, Wq, Wk, Wv, Wg, Wo, Xbq, Xbkv, Wt4, Wot);
  dim3 gp(32, 16);
  proj_kernel<<<gp, 256, 0, stream>>>(Xbq, Xbkv, Wt4, Qb, Kb, Vt, Gg);
  attn_kernel<<<1024, 256, 0, stream>>>(Qb, Kb, Vt, bias, Opart, Mpart, Lpart);
  combine_kernel<<<256, 256, 0, stream>>>(Opart, Mpart, Lpart, Gg, Og);
  dim3 go(32, 4);
  oproj_kernel<<<go, 256, 0, stream>>>(Og, Wot, out);
}